// Round 3
// baseline (357.437 us; speedup 1.0000x reference)
//
#include <hip/hip_runtime.h>
#include <hip/hip_bf16.h>
#include <math.h>

// Multi-head self-attention w/ RoPE, causal. B=2, S=2048, H=16, hd=64, D=1024.
// Inputs fp32 (per reference dtypes) -> convert to bf16 ws -> qkv GEMMs ->
// RoPE -> flash attention -> oproj -> fp32 output (bf16-rounded values).
// ws: xb(8MB) wq/wk/wv/wo(2MB ea) q,k,v(8MB ea) attn_out(8MB) = 48MB.

#define S_LEN 2048
#define NHEADS 16
#define HD 64
#define DM 1024

typedef __attribute__((ext_vector_type(8))) short bf16x8;  // MFMA A/B frag (4 VGPRs)
typedef __attribute__((ext_vector_type(4))) float f32x4;   // MFMA C/D frag

#define MFMA16(a, b, c) __builtin_amdgcn_mfma_f32_16x16x32_bf16((a), (b), (c), 0, 0, 0)
#define NEG_BIG (-1e30f)  // finite mask sentinel: exp(finite-finite) never NaN

// ---------------------------------------------------------------------------
// fp32 -> bf16 conversion pre-pass. y=0..3: x quarters; y=4..7: wq,wk,wv,wo.
// Each slice is 1M elements; thread converts 4 (float4 in, ushort4 out).
// ---------------------------------------------------------------------------
__global__ __launch_bounds__(256) void convert_kernel(
    const float* __restrict__ x,  const float* __restrict__ wq,
    const float* __restrict__ wk, const float* __restrict__ wv,
    const float* __restrict__ wo,
    __hip_bfloat16* __restrict__ xb,  __hip_bfloat16* __restrict__ wqb,
    __hip_bfloat16* __restrict__ wkb, __hip_bfloat16* __restrict__ wvb,
    __hip_bfloat16* __restrict__ wob)
{
    const int y = blockIdx.y;
    const float* src;
    __hip_bfloat16* dst;
    size_t off = 0;
    if (y < 4)      { src = x;  dst = xb;  off = (size_t)y * 1048576; }
    else if (y == 4) { src = wq; dst = wqb; }
    else if (y == 5) { src = wk; dst = wkb; }
    else if (y == 6) { src = wv; dst = wvb; }
    else             { src = wo; dst = wob; }

    const size_t i = off + ((size_t)blockIdx.x * 256 + threadIdx.x) * 4;
    float4 v = *(const float4*)(src + i);
    __hip_bfloat16 t[4] = { __float2bfloat16(v.x), __float2bfloat16(v.y),
                            __float2bfloat16(v.z), __float2bfloat16(v.w) };
    *(ushort4*)(dst + i) = *(ushort4*)t;
}

// ---------------------------------------------------------------------------
// GEMM: C[m,n] = sum_k A[m,k] * W[n,k]. Block tile 128x128, BK=32, 4 waves 2x2.
// A/B frag: lane holds [m(or n)=lane&15][k=quad*8+j]. C/D: col=lane&15,
// row=quad*4+reg (m89-verified).
// ---------------------------------------------------------------------------
__global__ __launch_bounds__(256) void qkv_kernel(
    const __hip_bfloat16* __restrict__ X,
    const __hip_bfloat16* __restrict__ Wq,
    const __hip_bfloat16* __restrict__ Wk,
    const __hip_bfloat16* __restrict__ Wv,
    __hip_bfloat16* __restrict__ qws,
    __hip_bfloat16* __restrict__ kws,
    __hip_bfloat16* __restrict__ vws)
{
    const int z = blockIdx.z;
    const __hip_bfloat16* __restrict__ W = (z == 0) ? Wq : (z == 1) ? Wk : Wv;
    __hip_bfloat16* __restrict__ out = (z == 0) ? qws : (z == 1) ? kws : vws;

    constexpr int LDK = 40;  // 32 + 8 pad, preserves 16B alignment
    __shared__ __align__(16) __hip_bfloat16 Asm[128 * LDK];
    __shared__ __align__(16) __hip_bfloat16 Bsm[128 * LDK];

    const int tid = threadIdx.x;
    const int wave = tid >> 6, lane = tid & 63;
    const int quad = lane >> 4, l15 = lane & 15;
    const int wm = (wave >> 1) * 64, wn = (wave & 1) * 64;
    const int m0 = blockIdx.y * 128, n0 = blockIdx.x * 128;

    f32x4 acc[4][4] = {};

    for (int k0 = 0; k0 < DM; k0 += 32) {
#pragma unroll
        for (int c = 0; c < 2; c++) {
            int idx = c * 2048 + tid * 8;
            int r = idx >> 5, kc = idx & 31;
            *(int4*)(&Asm[r * LDK + kc]) = *(const int4*)(X + (size_t)(m0 + r) * DM + k0 + kc);
            *(int4*)(&Bsm[r * LDK + kc]) = *(const int4*)(W + (size_t)(n0 + r) * DM + k0 + kc);
        }
        __syncthreads();
        bf16x8 af[4], bfv[4];
#pragma unroll
        for (int i = 0; i < 4; i++)
            af[i] = *(const bf16x8*)(&Asm[(wm + i * 16 + l15) * LDK + quad * 8]);
#pragma unroll
        for (int j = 0; j < 4; j++)
            bfv[j] = *(const bf16x8*)(&Bsm[(wn + j * 16 + l15) * LDK + quad * 8]);
#pragma unroll
        for (int i = 0; i < 4; i++)
#pragma unroll
            for (int j = 0; j < 4; j++)
                acc[i][j] = MFMA16(af[i], bfv[j], acc[i][j]);
        __syncthreads();
    }

#pragma unroll
    for (int i = 0; i < 4; i++) {
#pragma unroll
        for (int r = 0; r < 4; r++) {
            int m = m0 + wm + i * 16 + quad * 4 + r;
            int b = m >> 11, s = m & 2047;
#pragma unroll
            for (int j = 0; j < 4; j++) {
                int col = n0 + wn + j * 16 + l15;
                int h = col >> 6, d = col & 63;
                out[(((size_t)(b * NHEADS + h)) * S_LEN + s) * HD + d] =
                    __float2bfloat16(acc[i][j][r]);
            }
        }
    }
}

// ---------------------------------------------------------------------------
// RoPE in-place on q,k laid out (B,H,S,hd). One thread = 8 contiguous elems.
// ---------------------------------------------------------------------------
__global__ __launch_bounds__(256) void rope_kernel(
    __hip_bfloat16* __restrict__ q, __hip_bfloat16* __restrict__ k)
{
    __hip_bfloat16* __restrict__ p = (blockIdx.y == 0) ? q : k;
    const int gid = blockIdx.x * 256 + threadIdx.x;       // [0, 524288)
    const int e0 = gid * 8;
    const int s = (gid >> 3) & 2047;
    const int d0 = (gid & 7) * 8;

    int4 raw = *(const int4*)(p + e0);
    __hip_bfloat16* v = (__hip_bfloat16*)&raw;
#pragma unroll
    for (int i = 0; i < 4; i++) {
        int pi = (d0 >> 1) + i;                           // pair index [0,32)
        float theta = powf(10000.0f, -(float)(2 * pi) * (1.0f / 64.0f));
        float sn, cs;
        sincosf((float)s * theta, &sn, &cs);
        float x1 = __bfloat162float(v[2 * i]);
        float x2 = __bfloat162float(v[2 * i + 1]);
        v[2 * i]     = __float2bfloat16(x1 * cs - x2 * sn);
        v[2 * i + 1] = __float2bfloat16(x1 * sn + x2 * cs);
    }
    *(int4*)(p + e0) = raw;
}

// ---------------------------------------------------------------------------
// Flash attention: one block per (b*h, q-tile of 64). 4 waves x 16 q-rows.
// Finite-sentinel masking: NaN structurally impossible.
// ---------------------------------------------------------------------------
__global__ __launch_bounds__(256) void attn_kernel(
    const __hip_bfloat16* __restrict__ Qg,
    const __hip_bfloat16* __restrict__ Kg,
    const __hip_bfloat16* __restrict__ Vg,
    __hip_bfloat16* __restrict__ Og)  // (B,S,D) layout
{
    const int qi = blockIdx.x;
    const int bh = blockIdx.y;
    const int tid = threadIdx.x;
    const int w = tid >> 6, lane = tid & 63;
    const int quad = lane >> 4, l15 = lane & 15;
    const int q0 = qi * 64;
    const size_t base = (size_t)bh * S_LEN * HD;
    const __hip_bfloat16* Qb = Qg + base;
    const __hip_bfloat16* Kb = Kg + base;
    const __hip_bfloat16* Vb = Vg + base;

    __shared__ __align__(16) __hip_bfloat16 Pl[64 * 72];
    __shared__ __align__(16) __hip_bfloat16 Vt[64 * 72];

    const int qrow = q0 + w * 16 + l15;
    bf16x8 qf[2];
#pragma unroll
    for (int st = 0; st < 2; st++)
        qf[st] = *(const bf16x8*)(Qb + (size_t)qrow * HD + st * 32 + quad * 8);

    float m_i[4], l_i[4];
    f32x4 o[4] = {};
#pragma unroll
    for (int r = 0; r < 4; r++) { m_i[r] = NEG_BIG; l_i[r] = 0.f; }

    for (int j = 0; j <= qi; j++) {
        const int kv0 = j * 64;
        __syncthreads();  // protect Pl/Vt from previous iteration's readers

        // stage V transposed: Vt[d][kv]
#pragma unroll
        for (int c = 0; c < 2; c++) {
            int cc = c * 256 + tid;
            int kvr = cc & 63;
            int dc = (cc >> 6) * 8;
            int4 vv = *(const int4*)(Vb + (size_t)(kv0 + kvr) * HD + dc);
            const __hip_bfloat16* ve = (const __hip_bfloat16*)&vv;
#pragma unroll
            for (int t = 0; t < 8; t++) Vt[(dc + t) * 72 + kvr] = ve[t];
        }

        // S = Q K^T
        f32x4 sc[4] = {};
#pragma unroll
        for (int st = 0; st < 2; st++) {
#pragma unroll
            for (int t = 0; t < 4; t++) {
                bf16x8 kf = *(const bf16x8*)(Kb + (size_t)(kv0 + t * 16 + l15) * HD + st * 32 + quad * 8);
                sc[t] = MFMA16(qf[st], kf, sc[t]);
            }
        }

        // scale + causal mask (finite sentinel) + online softmax
        const bool diag = (j == qi);
        float rmax[4];
#pragma unroll
        for (int r = 0; r < 4; r++) rmax[r] = NEG_BIG;
#pragma unroll
        for (int t = 0; t < 4; t++) {
            int col = kv0 + t * 16 + l15;
#pragma unroll
            for (int r = 0; r < 4; r++) {
                int row = q0 + w * 16 + quad * 4 + r;
                float v = sc[t][r] * 0.125f;
                if (diag && col > row) v = NEG_BIG;
                sc[t][r] = v;
                rmax[r] = fmaxf(rmax[r], v);
            }
        }
#pragma unroll
        for (int off = 1; off < 16; off <<= 1)
#pragma unroll
            for (int r = 0; r < 4; r++) rmax[r] = fmaxf(rmax[r], __shfl_xor(rmax[r], off));

        float alpha[4], rsum[4];
#pragma unroll
        for (int r = 0; r < 4; r++) {
            float mn = fmaxf(m_i[r], rmax[r]);
            alpha[r] = __expf(m_i[r] - mn);
            m_i[r] = mn;
            rsum[r] = 0.f;
        }
#pragma unroll
        for (int t = 0; t < 4; t++)
#pragma unroll
            for (int r = 0; r < 4; r++) {
                float p = __expf(sc[t][r] - m_i[r]);
                sc[t][r] = p;
                rsum[r] += p;
            }
#pragma unroll
        for (int off = 1; off < 16; off <<= 1)
#pragma unroll
            for (int r = 0; r < 4; r++) rsum[r] += __shfl_xor(rsum[r], off);
#pragma unroll
        for (int r = 0; r < 4; r++) l_i[r] = l_i[r] * alpha[r] + rsum[r];
#pragma unroll
        for (int t = 0; t < 4; t++)
#pragma unroll
            for (int r = 0; r < 4; r++) o[t][r] *= alpha[r];

        // P -> LDS (C layout -> A-operand layout round trip)
#pragma unroll
        for (int t = 0; t < 4; t++)
#pragma unroll
            for (int r = 0; r < 4; r++)
                Pl[(w * 16 + quad * 4 + r) * 72 + t * 16 + l15] = __float2bfloat16(sc[t][r]);
        __syncthreads();

        // O += P V
#pragma unroll
        for (int st = 0; st < 2; st++) {
            bf16x8 pf = *(const bf16x8*)(&Pl[(w * 16 + l15) * 72 + st * 32 + quad * 8]);
#pragma unroll
            for (int t = 0; t < 4; t++) {
                bf16x8 vf = *(const bf16x8*)(&Vt[(t * 16 + l15) * 72 + st * 32 + quad * 8]);
                o[t] = MFMA16(pf, vf, o[t]);
            }
        }
    }

    const int b = bh >> 4, h = bh & 15;
#pragma unroll
    for (int t = 0; t < 4; t++)
#pragma unroll
        for (int r = 0; r < 4; r++) {
            int s = q0 + w * 16 + quad * 4 + r;
            int d = t * 16 + l15;
            float val = o[t][r] / l_i[r];
            Og[((size_t)(b * S_LEN + s)) * DM + h * HD + d] = __float2bfloat16(val);
        }
}

// ---------------------------------------------------------------------------
// Output projection: out = attn @ Wo^T -> d_out as FP32 (bf16-rounded values:
// if harness actually reads bf16 pairs, odd elems become 0.0 -> clean signal).
// ---------------------------------------------------------------------------
__global__ __launch_bounds__(256) void oproj_kernel(
    const __hip_bfloat16* __restrict__ A,
    const __hip_bfloat16* __restrict__ W,
    float* __restrict__ out)
{
    constexpr int LDK = 40;
    __shared__ __align__(16) __hip_bfloat16 Asm[128 * LDK];
    __shared__ __align__(16) __hip_bfloat16 Bsm[128 * LDK];

    const int tid = threadIdx.x;
    const int wave = tid >> 6, lane = tid & 63;
    const int quad = lane >> 4, l15 = lane & 15;
    const int wm = (wave >> 1) * 64, wn = (wave & 1) * 64;
    const int m0 = blockIdx.y * 128, n0 = blockIdx.x * 128;

    f32x4 acc[4][4] = {};

    for (int k0 = 0; k0 < DM; k0 += 32) {
#pragma unroll
        for (int c = 0; c < 2; c++) {
            int idx = c * 2048 + tid * 8;
            int r = idx >> 5, kc = idx & 31;
            *(int4*)(&Asm[r * LDK + kc]) = *(const int4*)(A + (size_t)(m0 + r) * DM + k0 + kc);
            *(int4*)(&Bsm[r * LDK + kc]) = *(const int4*)(W + (size_t)(n0 + r) * DM + k0 + kc);
        }
        __syncthreads();
        bf16x8 af[4], bfv[4];
#pragma unroll
        for (int i = 0; i < 4; i++)
            af[i] = *(const bf16x8*)(&Asm[(wm + i * 16 + l15) * LDK + quad * 8]);
#pragma unroll
        for (int j = 0; j < 4; j++)
            bfv[j] = *(const bf16x8*)(&Bsm[(wn + j * 16 + l15) * LDK + quad * 8]);
#pragma unroll
        for (int i = 0; i < 4; i++)
#pragma unroll
            for (int j = 0; j < 4; j++)
                acc[i][j] = MFMA16(af[i], bfv[j], acc[i][j]);
        __syncthreads();
    }

#pragma unroll
    for (int i = 0; i < 4; i++)
#pragma unroll
        for (int r = 0; r < 4; r++) {
            int m = m0 + wm + i * 16 + quad * 4 + r;
#pragma unroll
            for (int j = 0; j < 4; j++) {
                int col = n0 + wn + j * 16 + l15;
                __hip_bfloat16 b = __float2bfloat16(acc[i][j][r]);
                unsigned int u = ((unsigned int)(*(unsigned short*)&b)) << 16;
                out[(size_t)m * DM + col] = __uint_as_float(u);
            }
        }
}

// ---------------------------------------------------------------------------
extern "C" void kernel_launch(void* const* d_in, const int* in_sizes, int n_in,
                              void* d_out, int out_size, void* d_ws, size_t ws_size,
                              hipStream_t stream)
{
    const float* x  = (const float*)d_in[0];
    const float* wq = (const float*)d_in[1];
    const float* wk = (const float*)d_in[2];
    const float* wv = (const float*)d_in[3];
    const float* wo = (const float*)d_in[4];
    float* out = (float*)d_out;

    const size_t xe = (size_t)2 * S_LEN * DM;   // 4,194,304
    const size_t we = (size_t)DM * DM;          // 1,048,576
    __hip_bfloat16* xb  = (__hip_bfloat16*)d_ws;
    __hip_bfloat16* wqb = xb + xe;
    __hip_bfloat16* wkb = wqb + we;
    __hip_bfloat16* wvb = wkb + we;
    __hip_bfloat16* wob = wvb + we;
    __hip_bfloat16* qws = wob + we;
    __hip_bfloat16* kws = qws + xe;
    __hip_bfloat16* vws = kws + xe;
    __hip_bfloat16* aws = vws + xe;

    dim3 blk(256, 1, 1);
    convert_kernel<<<dim3(1024, 8, 1), blk, 0, stream>>>(x, wq, wk, wv, wo,
                                                         xb, wqb, wkb, wvb, wob);
    qkv_kernel<<<dim3(8, 32, 3), blk, 0, stream>>>(xb, wqb, wkb, wvb, qws, kws, vws);
    rope_kernel<<<dim3(2048, 2, 1), blk, 0, stream>>>(qws, kws);
    attn_kernel<<<dim3(32, 32, 1), blk, 0, stream>>>(qws, kws, vws, aws);
    oproj_kernel<<<dim3(8, 32, 1), blk, 0, stream>>>(aws, wob, out);
}

// Round 4
// 293.880 us; speedup vs baseline: 1.2163x; 1.2163x over previous
//
#include <hip/hip_runtime.h>
#include <hip/hip_bf16.h>
#include <math.h>

// Multi-head self-attention w/ RoPE, causal. B=2, S=2048, H=16, hd=64, D=1024.
// fp32 inputs -> bf16 ws -> qkv GEMMs (V stored transposed) -> RoPE ->
// barrier-free flash attention -> oproj -> fp32 output.
// ws: xb(8MB) wq/wk/wv/wo(2MB ea) q,k,vT(8MB ea) attn_out(8MB) = 48MB.

#define S_LEN 2048
#define NHEADS 16
#define HD 64
#define DM 1024

typedef __attribute__((ext_vector_type(8))) short bf16x8;  // MFMA A/B frag (4 VGPRs)
typedef __attribute__((ext_vector_type(4))) float f32x4;   // MFMA C/D frag

#define MFMA16(a, b, c) __builtin_amdgcn_mfma_f32_16x16x32_bf16((a), (b), (c), 0, 0, 0)
#define NEG_BIG (-1e30f)  // finite mask sentinel

// ---------------------------------------------------------------------------
// fp32 -> bf16 conversion pre-pass.
// ---------------------------------------------------------------------------
__global__ __launch_bounds__(256) void convert_kernel(
    const float* __restrict__ x,  const float* __restrict__ wq,
    const float* __restrict__ wk, const float* __restrict__ wv,
    const float* __restrict__ wo,
    __hip_bfloat16* __restrict__ xb,  __hip_bfloat16* __restrict__ wqb,
    __hip_bfloat16* __restrict__ wkb, __hip_bfloat16* __restrict__ wvb,
    __hip_bfloat16* __restrict__ wob)
{
    const int y = blockIdx.y;
    const float* src;
    __hip_bfloat16* dst;
    size_t off = 0;
    if (y < 4)      { src = x;  dst = xb;  off = (size_t)y * 1048576; }
    else if (y == 4) { src = wq; dst = wqb; }
    else if (y == 5) { src = wk; dst = wkb; }
    else if (y == 6) { src = wv; dst = wvb; }
    else             { src = wo; dst = wob; }

    const size_t i = off + ((size_t)blockIdx.x * 256 + threadIdx.x) * 4;
    float4 v = *(const float4*)(src + i);
    __hip_bfloat16 t[4] = { __float2bfloat16(v.x), __float2bfloat16(v.y),
                            __float2bfloat16(v.z), __float2bfloat16(v.w) };
    *(ushort4*)(dst + i) = *(ushort4*)t;
}

// ---------------------------------------------------------------------------
// GEMM: C[m,n] = sum_k A[m,k] * W[n,k]. 128x128 tile, BK=32, 4 waves 2x2.
// z=0,1 (Q,K): out (B,H,S,hd).  z=2 (V): out TRANSPOSED (B,H,hd,S) so the
// attention PV B-operand loads contiguously from global.
// ---------------------------------------------------------------------------
__global__ __launch_bounds__(256) void qkv_kernel(
    const __hip_bfloat16* __restrict__ X,
    const __hip_bfloat16* __restrict__ Wq,
    const __hip_bfloat16* __restrict__ Wk,
    const __hip_bfloat16* __restrict__ Wv,
    __hip_bfloat16* __restrict__ qws,
    __hip_bfloat16* __restrict__ kws,
    __hip_bfloat16* __restrict__ vws)
{
    const int z = blockIdx.z;
    const __hip_bfloat16* __restrict__ W = (z == 0) ? Wq : (z == 1) ? Wk : Wv;
    __hip_bfloat16* __restrict__ out = (z == 0) ? qws : (z == 1) ? kws : vws;

    constexpr int LDK = 40;
    __shared__ __align__(16) __hip_bfloat16 Asm[128 * LDK];
    __shared__ __align__(16) __hip_bfloat16 Bsm[128 * LDK];

    const int tid = threadIdx.x;
    const int wave = tid >> 6, lane = tid & 63;
    const int quad = lane >> 4, l15 = lane & 15;
    const int wm = (wave >> 1) * 64, wn = (wave & 1) * 64;
    const int m0 = blockIdx.y * 128, n0 = blockIdx.x * 128;

    f32x4 acc[4][4] = {};

    for (int k0 = 0; k0 < DM; k0 += 32) {
#pragma unroll
        for (int c = 0; c < 2; c++) {
            int idx = c * 2048 + tid * 8;
            int r = idx >> 5, kc = idx & 31;
            *(int4*)(&Asm[r * LDK + kc]) = *(const int4*)(X + (size_t)(m0 + r) * DM + k0 + kc);
            *(int4*)(&Bsm[r * LDK + kc]) = *(const int4*)(W + (size_t)(n0 + r) * DM + k0 + kc);
        }
        __syncthreads();
        bf16x8 af[4], bfv[4];
#pragma unroll
        for (int i = 0; i < 4; i++)
            af[i] = *(const bf16x8*)(&Asm[(wm + i * 16 + l15) * LDK + quad * 8]);
#pragma unroll
        for (int j = 0; j < 4; j++)
            bfv[j] = *(const bf16x8*)(&Bsm[(wn + j * 16 + l15) * LDK + quad * 8]);
#pragma unroll
        for (int i = 0; i < 4; i++)
#pragma unroll
            for (int j = 0; j < 4; j++)
                acc[i][j] = MFMA16(af[i], bfv[j], acc[i][j]);
        __syncthreads();
    }

#pragma unroll
    for (int i = 0; i < 4; i++) {
#pragma unroll
        for (int r = 0; r < 4; r++) {
            int m = m0 + wm + i * 16 + quad * 4 + r;
            int b = m >> 11, s = m & 2047;
#pragma unroll
            for (int j = 0; j < 4; j++) {
                int col = n0 + wn + j * 16 + l15;
                int h = col >> 6, d = col & 63;
                size_t idx = (z == 2)
                    ? (((size_t)(b * NHEADS + h)) * HD + d) * S_LEN + s    // V^T: (B,H,hd,S)
                    : (((size_t)(b * NHEADS + h)) * S_LEN + s) * HD + d;   // Q,K: (B,H,S,hd)
                out[idx] = __float2bfloat16(acc[i][j][r]);
            }
        }
    }
}

// ---------------------------------------------------------------------------
// RoPE in-place on q,k laid out (B,H,S,hd).
// ---------------------------------------------------------------------------
__global__ __launch_bounds__(256) void rope_kernel(
    __hip_bfloat16* __restrict__ q, __hip_bfloat16* __restrict__ k)
{
    __hip_bfloat16* __restrict__ p = (blockIdx.y == 0) ? q : k;
    const int gid = blockIdx.x * 256 + threadIdx.x;       // [0, 524288)
    const int e0 = gid * 8;
    const int s = (gid >> 3) & 2047;
    const int d0 = (gid & 7) * 8;

    int4 raw = *(const int4*)(p + e0);
    __hip_bfloat16* v = (__hip_bfloat16*)&raw;
#pragma unroll
    for (int i = 0; i < 4; i++) {
        int pi = (d0 >> 1) + i;
        float theta = powf(10000.0f, -(float)(2 * pi) * (1.0f / 64.0f));
        float sn, cs;
        sincosf((float)s * theta, &sn, &cs);
        float x1 = __bfloat162float(v[2 * i]);
        float x2 = __bfloat162float(v[2 * i + 1]);
        v[2 * i]     = __float2bfloat16(x1 * cs - x2 * sn);
        v[2 * i + 1] = __float2bfloat16(x1 * sn + x2 * cs);
    }
    *(int4*)(p + e0) = raw;
}

// ---------------------------------------------------------------------------
// Barrier-free flash attention. Block = 4 independent waves, 16 q-rows each.
// Block processes q-tile pair (bx, 31-bx): every block = exactly 33 kv-iters.
// K register-double-buffered; V^T frags loaded straight from global; the P
// C-layout -> A-layout transform goes through a WAVE-PRIVATE LDS region
// (rows [w*16, w*16+16) written+read by the same wave -> no __syncthreads).
// ---------------------------------------------------------------------------
__global__ __launch_bounds__(256) void attn_kernel(
    const __hip_bfloat16* __restrict__ Qg,
    const __hip_bfloat16* __restrict__ Kg,
    const __hip_bfloat16* __restrict__ Vtg,  // (B,H,hd,S)
    __hip_bfloat16* __restrict__ Og)         // (B,S,D)
{
    const int bh = blockIdx.y;
    const int tid = threadIdx.x;
    const int w = tid >> 6, lane = tid & 63;
    const int quad = lane >> 4, l15 = lane & 15;
    const size_t base = (size_t)bh * S_LEN * HD;
    const __hip_bfloat16* Qb = Qg + base;
    const __hip_bfloat16* Kb = Kg + base;
    const __hip_bfloat16* Vtb = Vtg + base;
    const int b = bh >> 4, h = bh & 15;

    __shared__ __align__(16) __hip_bfloat16 Pl[64 * 72];
    __hip_bfloat16* Prow = &Pl[w * 16 * 72];  // wave-private 16x64(+8 pad)

#pragma unroll 1
    for (int half = 0; half < 2; half++) {
        const int qi = (half == 0) ? blockIdx.x : 31 - blockIdx.x;
        const int q0 = qi * 64;
        const int qrow = q0 + w * 16 + l15;

        bf16x8 qf[2];
#pragma unroll
        for (int st = 0; st < 2; st++)
            qf[st] = *(const bf16x8*)(Qb + (size_t)qrow * HD + st * 32 + quad * 8);

        float m_i[4], l_i[4];
        f32x4 o[4] = {};
#pragma unroll
        for (int r = 0; r < 4; r++) { m_i[r] = NEG_BIG; l_i[r] = 0.f; }

        // prefetch K tile 0
        bf16x8 kf[2][4];
#pragma unroll
        for (int st = 0; st < 2; st++)
#pragma unroll
            for (int t = 0; t < 4; t++)
                kf[st][t] = *(const bf16x8*)(Kb + (size_t)(t * 16 + l15) * HD + st * 32 + quad * 8);

#pragma unroll 1
        for (int j = 0; j <= qi; j++) {
            const int kv0 = j * 64;

            // issue V^T frag loads early (used after softmax)
            bf16x8 vf[2][4];
#pragma unroll
            for (int st = 0; st < 2; st++)
#pragma unroll
                for (int t = 0; t < 4; t++)
                    vf[st][t] = *(const bf16x8*)(Vtb + (size_t)(t * 16 + l15) * S_LEN + kv0 + st * 32 + quad * 8);

            // S = Q K^T with current K frags
            f32x4 sc[4] = {};
#pragma unroll
            for (int st = 0; st < 2; st++)
#pragma unroll
                for (int t = 0; t < 4; t++)
                    sc[t] = MFMA16(qf[st], kf[st][t], sc[t]);

            // prefetch next K tile (clamped; last-iter loads are discarded)
            const int kvn = (j < qi) ? kv0 + 64 : kv0;
            bf16x8 kfn[2][4];
#pragma unroll
            for (int st = 0; st < 2; st++)
#pragma unroll
                for (int t = 0; t < 4; t++)
                    kfn[st][t] = *(const bf16x8*)(Kb + (size_t)(kvn + t * 16 + l15) * HD + st * 32 + quad * 8);

            // scale + causal mask + online softmax
            const bool diag = (j == qi);
            float rmax[4];
#pragma unroll
            for (int r = 0; r < 4; r++) rmax[r] = NEG_BIG;
#pragma unroll
            for (int t = 0; t < 4; t++) {
                int col = kv0 + t * 16 + l15;
#pragma unroll
                for (int r = 0; r < 4; r++) {
                    int row = q0 + w * 16 + quad * 4 + r;
                    float v = sc[t][r] * 0.125f;
                    if (diag && col > row) v = NEG_BIG;
                    sc[t][r] = v;
                    rmax[r] = fmaxf(rmax[r], v);
                }
            }
#pragma unroll
            for (int off = 1; off < 16; off <<= 1)
#pragma unroll
                for (int r = 0; r < 4; r++) rmax[r] = fmaxf(rmax[r], __shfl_xor(rmax[r], off));

            float alpha[4], rsum[4];
#pragma unroll
            for (int r = 0; r < 4; r++) {
                float mn = fmaxf(m_i[r], rmax[r]);
                alpha[r] = __expf(m_i[r] - mn);
                m_i[r] = mn;
                rsum[r] = 0.f;
            }
#pragma unroll
            for (int t = 0; t < 4; t++)
#pragma unroll
                for (int r = 0; r < 4; r++) {
                    float p = __expf(sc[t][r] - m_i[r]);
                    sc[t][r] = p;
                    rsum[r] += p;
                }
#pragma unroll
            for (int off = 1; off < 16; off <<= 1)
#pragma unroll
                for (int r = 0; r < 4; r++) rsum[r] += __shfl_xor(rsum[r], off);
#pragma unroll
            for (int r = 0; r < 4; r++) l_i[r] = l_i[r] * alpha[r] + rsum[r];
#pragma unroll
            for (int t = 0; t < 4; t++)
#pragma unroll
                for (int r = 0; r < 4; r++) o[t][r] *= alpha[r];

            // P: C layout -> A-operand layout, wave-private LDS round trip
#pragma unroll
            for (int t = 0; t < 4; t++)
#pragma unroll
                for (int r = 0; r < 4; r++)
                    Prow[(quad * 4 + r) * 72 + t * 16 + l15] = __float2bfloat16(sc[t][r]);

            // O += P V
#pragma unroll
            for (int st = 0; st < 2; st++) {
                bf16x8 pf = *(const bf16x8*)(&Prow[l15 * 72 + st * 32 + quad * 8]);
#pragma unroll
                for (int t = 0; t < 4; t++)
                    o[t] = MFMA16(pf, vf[st][t], o[t]);
            }

            // rotate K double buffer
#pragma unroll
            for (int st = 0; st < 2; st++)
#pragma unroll
                for (int t = 0; t < 4; t++)
                    kf[st][t] = kfn[st][t];
        }

        // epilogue: O/l -> (B,S,D)
#pragma unroll
        for (int t = 0; t < 4; t++)
#pragma unroll
            for (int r = 0; r < 4; r++) {
                int s = q0 + w * 16 + quad * 4 + r;
                int d = t * 16 + l15;
                float val = o[t][r] / l_i[r];
                Og[((size_t)(b * S_LEN + s)) * DM + h * HD + d] = __float2bfloat16(val);
            }
    }
}

// ---------------------------------------------------------------------------
// Output projection: out = attn @ Wo^T -> d_out as fp32 (bf16-rounded).
// ---------------------------------------------------------------------------
__global__ __launch_bounds__(256) void oproj_kernel(
    const __hip_bfloat16* __restrict__ A,
    const __hip_bfloat16* __restrict__ W,
    float* __restrict__ out)
{
    constexpr int LDK = 40;
    __shared__ __align__(16) __hip_bfloat16 Asm[128 * LDK];
    __shared__ __align__(16) __hip_bfloat16 Bsm[128 * LDK];

    const int tid = threadIdx.x;
    const int wave = tid >> 6, lane = tid & 63;
    const int quad = lane >> 4, l15 = lane & 15;
    const int wm = (wave >> 1) * 64, wn = (wave & 1) * 64;
    const int m0 = blockIdx.y * 128, n0 = blockIdx.x * 128;

    f32x4 acc[4][4] = {};

    for (int k0 = 0; k0 < DM; k0 += 32) {
#pragma unroll
        for (int c = 0; c < 2; c++) {
            int idx = c * 2048 + tid * 8;
            int r = idx >> 5, kc = idx & 31;
            *(int4*)(&Asm[r * LDK + kc]) = *(const int4*)(A + (size_t)(m0 + r) * DM + k0 + kc);
            *(int4*)(&Bsm[r * LDK + kc]) = *(const int4*)(W + (size_t)(n0 + r) * DM + k0 + kc);
        }
        __syncthreads();
        bf16x8 af[4], bfv[4];
#pragma unroll
        for (int i = 0; i < 4; i++)
            af[i] = *(const bf16x8*)(&Asm[(wm + i * 16 + l15) * LDK + quad * 8]);
#pragma unroll
        for (int j = 0; j < 4; j++)
            bfv[j] = *(const bf16x8*)(&Bsm[(wn + j * 16 + l15) * LDK + quad * 8]);
#pragma unroll
        for (int i = 0; i < 4; i++)
#pragma unroll
            for (int j = 0; j < 4; j++)
                acc[i][j] = MFMA16(af[i], bfv[j], acc[i][j]);
        __syncthreads();
    }

#pragma unroll
    for (int i = 0; i < 4; i++)
#pragma unroll
        for (int r = 0; r < 4; r++) {
            int m = m0 + wm + i * 16 + quad * 4 + r;
#pragma unroll
            for (int j = 0; j < 4; j++) {
                int col = n0 + wn + j * 16 + l15;
                __hip_bfloat16 bb = __float2bfloat16(acc[i][j][r]);
                unsigned int u = ((unsigned int)(*(unsigned short*)&bb)) << 16;
                out[(size_t)m * DM + col] = __uint_as_float(u);
            }
        }
}

// ---------------------------------------------------------------------------
extern "C" void kernel_launch(void* const* d_in, const int* in_sizes, int n_in,
                              void* d_out, int out_size, void* d_ws, size_t ws_size,
                              hipStream_t stream)
{
    const float* x  = (const float*)d_in[0];
    const float* wq = (const float*)d_in[1];
    const float* wk = (const float*)d_in[2];
    const float* wv = (const float*)d_in[3];
    const float* wo = (const float*)d_in[4];
    float* out = (float*)d_out;

    const size_t xe = (size_t)2 * S_LEN * DM;
    const size_t we = (size_t)DM * DM;
    __hip_bfloat16* xb  = (__hip_bfloat16*)d_ws;
    __hip_bfloat16* wqb = xb + xe;
    __hip_bfloat16* wkb = wqb + we;
    __hip_bfloat16* wvb = wkb + we;
    __hip_bfloat16* wob = wvb + we;
    __hip_bfloat16* qws = wob + we;
    __hip_bfloat16* kws = qws + xe;
    __hip_bfloat16* vws = kws + xe;   // V^T (B,H,hd,S)
    __hip_bfloat16* aws = vws + xe;

    dim3 blk(256, 1, 1);
    convert_kernel<<<dim3(1024, 8, 1), blk, 0, stream>>>(x, wq, wk, wv, wo,
                                                         xb, wqb, wkb, wvb, wob);
    qkv_kernel<<<dim3(8, 32, 3), blk, 0, stream>>>(xb, wqb, wkb, wvb, qws, kws, vws);
    rope_kernel<<<dim3(2048, 2, 1), blk, 0, stream>>>(qws, kws);
    attn_kernel<<<dim3(16, 32, 1), blk, 0, stream>>>(qws, kws, vws, aws);
    oproj_kernel<<<dim3(8, 32, 1), blk, 0, stream>>>(aws, wob, out);
}